// Round 1
// 4431.498 us; speedup vs baseline: 1.0868x; 1.0868x over previous
//
#include <hip/hip_runtime.h>
#include <math.h>

// ---------------- problem constants ----------------
#define B_   8
#define D_   768
#define H_   12
#define L_   12
#define NTOK 785            // 1 + 28*28
#define NPAT 784
#define MTOT (B_ * NTOK)    // 6280
#define MPAT (B_ * NPAT)    // 6272
#define MPAD 6400           // padded row count (multiple of 128)
#define DFF  3072
#define EPS_ 1e-5f

typedef unsigned short u16;
typedef unsigned int   u32;
typedef short s16x8 __attribute__((ext_vector_type(8)));
typedef float f32x4 __attribute__((ext_vector_type(4)));

__device__ __forceinline__ u16 f2b(float f) {
    u32 u = __float_as_uint(f);
    u += 0x7fffu + ((u >> 16) & 1u);   // RNE
    return (u16)(u >> 16);
}
__device__ __forceinline__ float b2f(u16 s) {
    return __uint_as_float(((u32)s) << 16);
}
__device__ __forceinline__ void gload_lds16(const void* g, void* l) {
    __builtin_amdgcn_global_load_lds(
        (const __attribute__((address_space(1))) void*)g,
        (__attribute__((address_space(3))) void*)l, 16, 0, 0);
}
__device__ __forceinline__ float gelu_exact(float x) {
    return 0.5f * x * (1.0f + erff(x * 0.70710678118654752f));
}

// ---------------- bf16 MFMA GEMM ----------------
// C[M,N] = A[M,K](bf16) @ W + bias, with WT[N,K](bf16) = W^T.
// BM x 128 tile (BM in {64,128}), BK=32, 256 threads (4 waves),
// waves in a 2x2 grid: each wave owns (BM/2) x 64 of the tile as
// MI x 4 mfma_f32_16x16x32_bf16 fragments, MI = BM/32.
// BM=64 exists to raise block concurrency on thin-N launches (N=768):
// grid 6x50=300 blocks @BM=128 left ~1 block/CU (Occupancy 11%) -> no
// cross-block overlap to hide the per-K-step barrier drain.
// MODE: 0 bias, 1 bias+gelu, 2 bias+residual(R fp32). OUTBF: 1 -> bf16 out.
template <int BM, int MODE, int OUTBF>
__global__ __launch_bounds__(256) void mfma_gemm(
    const u16* __restrict__ A, const u16* __restrict__ WT,
    const float* __restrict__ bias, const float* __restrict__ R,
    void* __restrict__ Cout, int M, int N, int K)
{
    constexpr int MI = BM / 32;          // A row-fragments per wave
    __shared__ u16 As[BM * 32];
    __shared__ u16 Bs[128 * 32];

    const int bm = blockIdx.y * BM;
    const int bn = blockIdx.x * 128;
    const int t  = threadIdx.x;
    const int wv = t >> 6, ln = t & 63;
    const int wr = wv >> 1, wc = wv & 1;

    f32x4 acc[MI][4];
    const f32x4 z4 = {0.f, 0.f, 0.f, 0.f};
#pragma unroll
    for (int i = 0; i < MI; i++)
#pragma unroll
        for (int j = 0; j < 4; j++) acc[i][j] = z4;

    const int lrow = ln & 15;
    const int kq   = (ln >> 4) * 8;

    for (int kt = 0; kt < K; kt += 32) {
        __syncthreads();
#pragma unroll
        for (int g = 0; g < BM / 64; g++) {              // A: BM*4 chunks
            const int c = g * 256 + wv * 64 + ln;        // 16B chunk id
            u16* ldsA = As + (g * 256 + wv * 64) * 8;    // wave-uniform base
            gload_lds16(A + (size_t)(bm + (c >> 2)) * K + kt + (c & 3) * 8, ldsA);
        }
#pragma unroll
        for (int g = 0; g < 2; g++) {                    // B: 512 chunks
            const int c = g * 256 + wv * 64 + ln;
            u16* ldsB = Bs + (g * 256 + wv * 64) * 8;
            gload_lds16(WT + (size_t)(bn + (c >> 2)) * K + kt + (c & 3) * 8, ldsB);
        }
        __syncthreads();

        s16x8 af[MI], bf[4];
#pragma unroll
        for (int i = 0; i < MI; i++)
            af[i] = *(const s16x8*)(As + (wr * (BM / 2) + i * 16 + lrow) * 32 + kq);
#pragma unroll
        for (int j = 0; j < 4; j++)
            bf[j] = *(const s16x8*)(Bs + (wc * 64 + j * 16 + lrow) * 32 + kq);
#pragma unroll
        for (int i = 0; i < MI; i++)
#pragma unroll
            for (int j = 0; j < 4; j++)
                acc[i][j] = __builtin_amdgcn_mfma_f32_16x16x32_bf16(
                    af[i], bf[j], acc[i][j], 0, 0, 0);
    }

    const int col_l = ln & 15;
    const int rq    = (ln >> 4) * 4;
#pragma unroll
    for (int j = 0; j < 4; j++) {
        const int col = bn + wc * 64 + j * 16 + col_l;
        const float bj = bias[col];
#pragma unroll
        for (int i = 0; i < MI; i++) {
            const int row0 = bm + wr * (BM / 2) + i * 16 + rq;
#pragma unroll
            for (int rg = 0; rg < 4; rg++) {
                const int row = row0 + rg;
                if (row >= M) continue;
                float v = acc[i][j][rg] + bj;
                if (MODE == 1) v = gelu_exact(v);
                if (MODE == 2) v += R[(size_t)row * N + col];
                if (OUTBF) ((u16*)Cout)[(size_t)row * N + col] = f2b(v);
                else       ((float*)Cout)[(size_t)row * N + col] = v;
            }
        }
    }
}

// ---------------- weight convert + transpose: W[K,N] f32 -> WT[N,K] bf16 ----
// blockIdx.z = layer; per-layer stride is K*N elements for both src and dst.
__global__ __launch_bounds__(256) void wt_kernel(
    const float* __restrict__ W, u16* __restrict__ WT, int K, int N)
{
    const size_t lz = blockIdx.z;
    W  += lz * (size_t)K * N;
    WT += lz * (size_t)K * N;
    __shared__ float tile[32][33];
    const int n0 = blockIdx.x * 32, k0 = blockIdx.y * 32;
    const int r = threadIdx.x >> 3, c4 = (threadIdx.x & 7) * 4;
    const float4 v = *(const float4*)(W + (size_t)(k0 + r) * N + n0 + c4);
    tile[r][c4 + 0] = v.x; tile[r][c4 + 1] = v.y;
    tile[r][c4 + 2] = v.z; tile[r][c4 + 3] = v.w;
    __syncthreads();
    ushort4 o = make_ushort4(f2b(tile[c4 + 0][r]), f2b(tile[c4 + 1][r]),
                             f2b(tile[c4 + 2][r]), f2b(tile[c4 + 3][r]));
    *(ushort4*)(WT + (size_t)(n0 + r) * K + k0 + c4) = o;
}

// ---------------- flat f32 -> bf16 convert ----------------
__global__ __launch_bounds__(256) void flatcvt_kernel(
    const float* __restrict__ in, u16* __restrict__ out, int n4)
{
    const int i = blockIdx.x * 256 + threadIdx.x;
    if (i >= n4) return;
    const float4 v = ((const float4*)in)[i];
    ((ushort4*)out)[i] = make_ushort4(f2b(v.x), f2b(v.y), f2b(v.z), f2b(v.w));
}

// ---------------- LayerNorm (fp32 in, bf16 or fp32 out) ----------------
__device__ __forceinline__ float block_sum(float s, float* red) {
#pragma unroll
    for (int off = 32; off; off >>= 1) s += __shfl_down(s, off, 64);
    const int wid = threadIdx.x >> 6;
    if ((threadIdx.x & 63) == 0) red[wid] = s;
    __syncthreads();
    if (threadIdx.x == 0) red[0] = red[0] + red[1] + red[2] + red[3];
    __syncthreads();
    const float r = red[0];
    __syncthreads();
    return r;
}

template <int OUTBF>
__global__ __launch_bounds__(256) void ln_kernel(
    const float* __restrict__ X, const float* __restrict__ g,
    const float* __restrict__ b, void* __restrict__ Y, size_t row_stride_in)
{
    __shared__ float red[4];
    const int row = blockIdx.x;
    const int t = threadIdx.x;
    const float* x = X + (size_t)row * row_stride_in;

    const float v0 = x[t], v1 = x[t + 256], v2 = x[t + 512];
    const float mean = block_sum(v0 + v1 + v2, red) * (1.0f / 768.0f);
    const float d0 = v0 - mean, d1 = v1 - mean, d2 = v2 - mean;
    const float var = block_sum(d0 * d0 + d1 * d1 + d2 * d2, red) * (1.0f / 768.0f);
    const float rs = rsqrtf(var + EPS_);

    const float o0 = d0 * rs * g[t] + b[t];
    const float o1 = d1 * rs * g[t + 256] + b[t + 256];
    const float o2 = d2 * rs * g[t + 512] + b[t + 512];
    if (OUTBF) {
        u16* y = (u16*)Y + (size_t)row * 768;
        y[t] = f2b(o0); y[t + 256] = f2b(o1); y[t + 512] = f2b(o2);
    } else {
        float* y = (float*)Y + (size_t)row * 768;
        y[t] = o0; y[t + 256] = o1; y[t + 512] = o2;
    }
}

// ---------------- MFMA flash attention ----------------
// Block: one (b,h), 128 q-rows; 4 waves x 32 q-rows (2 row-tiles of 16).
// K-tiles of 64 tokens. QK^T and PV via mfma_f32_16x16x32_bf16 (NT form).
#define AQB  128
#define AKT  64
#define KSTR 72   // u16 row stride: 144B rows -> b128 frag reads at bank floor

__global__ __launch_bounds__(256) void attn_kernel(
    const u16* __restrict__ qkv, u16* __restrict__ out)
{
    __shared__ u16 Ks[AKT * KSTR];
    __shared__ u16 Vt[64 * KSTR];
    __shared__ u16 Ps[4 * 32 * KSTR];

    const int bh = blockIdx.y;
    const int b  = bh / H_, hh = bh % H_;
    const int q0 = blockIdx.x * AQB;
    const int t  = threadIdx.x;
    const int w  = t >> 6, ln = t & 63;
    const int lrow = ln & 15, quad = ln >> 4;
    const size_t tokbase = (size_t)b * NTOK;

    s16x8 aq[2][2];
#pragma unroll
    for (int rowt = 0; rowt < 2; rowt++) {
        int qr = q0 + w * 32 + rowt * 16 + lrow;
        if (qr > NTOK - 1) qr = NTOK - 1;
        const u16* qp = qkv + (tokbase + qr) * 2304 + hh * 64 + quad * 8;
        aq[rowt][0] = *(const s16x8*)(qp);
        aq[rowt][1] = *(const s16x8*)(qp + 32);
    }

    f32x4 acc_o[2][4];
    const f32x4 z4 = {0.f, 0.f, 0.f, 0.f};
#pragma unroll
    for (int i = 0; i < 2; i++)
#pragma unroll
        for (int j = 0; j < 4; j++) acc_o[i][j] = z4;
    float m_r[2][4], l_r[2][4];
#pragma unroll
    for (int i = 0; i < 2; i++)
#pragma unroll
        for (int j = 0; j < 4; j++) { m_r[i][j] = -1e30f; l_r[i][j] = 0.f; }

    for (int j0 = 0; j0 < NTOK; j0 += AKT) {
        __syncthreads();
#pragma unroll
        for (int g = 0; g < 2; g++) {
            const int c = g * 256 + t;
            const int j = c >> 3, dc = c & 7;
            int jj = j0 + j; if (jj > NTOK - 1) jj = NTOK - 1;
            const s16x8 kv = *(const s16x8*)(
                qkv + (tokbase + jj) * 2304 + 768 + hh * 64 + dc * 8);
            *(s16x8*)(Ks + j * KSTR + dc * 8) = kv;
        }
#pragma unroll
        for (int g = 0; g < 2; g++) {
            const int c = g * 256 + t;
            const int j = c & 63, dc = c >> 6;
            int jj = j0 + j; if (jj > NTOK - 1) jj = NTOK - 1;
            const s16x8 vv = *(const s16x8*)(
                qkv + (tokbase + jj) * 2304 + 1536 + hh * 64 + dc * 8);
#pragma unroll
            for (int e = 0; e < 8; e++)
                Vt[(dc * 8 + e) * KSTR + j] = (u16)((const short*)&vv)[e];
        }
        __syncthreads();

        f32x4 acc_s[2][4];
#pragma unroll
        for (int i = 0; i < 2; i++)
#pragma unroll
            for (int j = 0; j < 4; j++) acc_s[i][j] = z4;
#pragma unroll
        for (int jt = 0; jt < 4; jt++) {
            const s16x8 bk0 =
                *(const s16x8*)(Ks + (jt * 16 + lrow) * KSTR + quad * 8);
            const s16x8 bk1 =
                *(const s16x8*)(Ks + (jt * 16 + lrow) * KSTR + 32 + quad * 8);
#pragma unroll
            for (int rowt = 0; rowt < 2; rowt++) {
                acc_s[rowt][jt] = __builtin_amdgcn_mfma_f32_16x16x32_bf16(
                    aq[rowt][0], bk0, acc_s[rowt][jt], 0, 0, 0);
                acc_s[rowt][jt] = __builtin_amdgcn_mfma_f32_16x16x32_bf16(
                    aq[rowt][1], bk1, acc_s[rowt][jt], 0, 0, 0);
            }
        }
        const f32x4 ninf = {-1e30f, -1e30f, -1e30f, -1e30f};
#pragma unroll
        for (int jt = 0; jt < 4; jt++) {
            const bool valid = (j0 + jt * 16 + lrow) < NTOK;
#pragma unroll
            for (int rowt = 0; rowt < 2; rowt++)
                acc_s[rowt][jt] = valid ? acc_s[rowt][jt] * 0.125f : ninf;
        }

#pragma unroll
        for (int rowt = 0; rowt < 2; rowt++) {
#pragma unroll
            for (int rg = 0; rg < 4; rg++) {
                float mx = fmaxf(fmaxf(acc_s[rowt][0][rg], acc_s[rowt][1][rg]),
                                 fmaxf(acc_s[rowt][2][rg], acc_s[rowt][3][rg]));
                mx = fmaxf(mx, __shfl_xor(mx, 1, 64));
                mx = fmaxf(mx, __shfl_xor(mx, 2, 64));
                mx = fmaxf(mx, __shfl_xor(mx, 4, 64));
                mx = fmaxf(mx, __shfl_xor(mx, 8, 64));
                const float nm = fmaxf(m_r[rowt][rg], mx);
                const float al = __expf(m_r[rowt][rg] - nm);
                m_r[rowt][rg] = nm;
                u16* prow = Ps + (size_t)(w * 32 + rowt * 16 + quad * 4 + rg) * KSTR
                            + lrow;
                float ps = 0.f;
#pragma unroll
                for (int jt = 0; jt < 4; jt++) {
                    const float p = __expf(acc_s[rowt][jt][rg] - nm);
                    ps += p;
                    prow[jt * 16] = f2b(p);
                }
                ps += __shfl_xor(ps, 1, 64);
                ps += __shfl_xor(ps, 2, 64);
                ps += __shfl_xor(ps, 4, 64);
                ps += __shfl_xor(ps, 8, 64);
                l_r[rowt][rg] = l_r[rowt][rg] * al + ps;
#pragma unroll
                for (int dt = 0; dt < 4; dt++) acc_o[rowt][dt][rg] *= al;
            }
        }

#pragma unroll
        for (int jc = 0; jc < 2; jc++) {
            const s16x8 ap0 = *(const s16x8*)(
                Ps + (w * 32 + lrow) * KSTR + jc * 32 + quad * 8);
            const s16x8 ap1 = *(const s16x8*)(
                Ps + (w * 32 + 16 + lrow) * KSTR + jc * 32 + quad * 8);
#pragma unroll
            for (int dt = 0; dt < 4; dt++) {
                const s16x8 bv = *(const s16x8*)(
                    Vt + (dt * 16 + lrow) * KSTR + jc * 32 + quad * 8);
                acc_o[0][dt] = __builtin_amdgcn_mfma_f32_16x16x32_bf16(
                    ap0, bv, acc_o[0][dt], 0, 0, 0);
                acc_o[1][dt] = __builtin_amdgcn_mfma_f32_16x16x32_bf16(
                    ap1, bv, acc_o[1][dt], 0, 0, 0);
            }
        }
    }

#pragma unroll
    for (int rowt = 0; rowt < 2; rowt++) {
#pragma unroll
        for (int rg = 0; rg < 4; rg++) {
            const int tok = q0 + w * 32 + rowt * 16 + quad * 4 + rg;
            if (tok >= NTOK) continue;
            const float inv = 1.0f / l_r[rowt][rg];
            u16* dst = out + (tokbase + tok) * D_ + hh * 64 + lrow;
#pragma unroll
            for (int dt = 0; dt < 4; dt++)
                dst[dt * 16] = f2b(acc_o[rowt][dt][rg] * inv);
        }
    }
}

// ---------------- im2col (fp32 -> bf16 patches) ----------------
__global__ __launch_bounds__(256) void im2col_kernel(
    const float* __restrict__ x, u16* __restrict__ patches)
{
    const int idx = blockIdx.x * 256 + threadIdx.x;  // over MPAT*96 8-chunks
    if (idx >= MPAT * 96) return;
    const int prow = idx / 96;
    const int c8 = (idx % 96) * 8;
    const int bb = prow / NPAT;
    const int pp = prow % NPAT;
    const int gy = pp / 28, gx = pp % 28;
    const int c = c8 >> 8;
    const int rem = c8 & 255;
    const int py = rem >> 4, px = rem & 15;
    const float* src =
        x + (((size_t)(bb * 3 + c) * 448 + gy * 16 + py) * 448 + gx * 16 + px);
    const float4 a = *(const float4*)src;
    const float4 bq = *(const float4*)(src + 4);
    u16* dst = patches + (size_t)prow * 768 + c8;
    uint4 w4;
    w4.x = (u32)f2b(a.x) | ((u32)f2b(a.y) << 16);
    w4.y = (u32)f2b(a.z) | ((u32)f2b(a.w) << 16);
    w4.z = (u32)f2b(bq.x) | ((u32)f2b(bq.y) << 16);
    w4.w = (u32)f2b(bq.z) | ((u32)f2b(bq.w) << 16);
    *(uint4*)dst = w4;
}

// ---------------- assemble h = [cls|conv_out] + pos (fp32) ----------------
__global__ __launch_bounds__(256) void assemble_kernel(
    const float* __restrict__ conv_out, const float* __restrict__ cls,
    const float* __restrict__ pos, float* __restrict__ h)
{
    const int idx = blockIdx.x * 256 + threadIdx.x;  // over MTOT*192 float4s
    if (idx >= MTOT * 192) return;
    const int row = idx / 192;
    const int d = (idx % 192) * 4;
    const int bb = row / NTOK, n = row % NTOK;
    const float4 pv = *(const float4*)(pos + (size_t)n * 768 + d);
    float4 v;
    if (n == 0) {
        const float4 cv = *(const float4*)(cls + d);
        v = make_float4(cv.x + pv.x, cv.y + pv.y, cv.z + pv.z, cv.w + pv.w);
    } else {
        const float4 co =
            *(const float4*)(conv_out + (size_t)(bb * NPAT + n - 1) * 768 + d);
        v = make_float4(co.x + pv.x, co.y + pv.y, co.z + pv.z, co.w + pv.w);
    }
    *(float4*)(h + (size_t)row * 768 + d) = v;
}

// ---------------- host orchestration ----------------
extern "C" void kernel_launch(void* const* d_in, const int* in_sizes, int n_in,
                              void* d_out, int out_size, void* d_ws, size_t ws_size,
                              hipStream_t stream)
{
    const float* x      = (const float*)d_in[0];
    const float* conv_w = (const float*)d_in[1];
    const float* conv_b = (const float*)d_in[2];
    const float* cls    = (const float*)d_in[3];
    const float* pos    = (const float*)d_in[4];
    const float* ln1_g  = (const float*)d_in[5];
    const float* ln1_b  = (const float*)d_in[6];
    const float* qkv_w  = (const float*)d_in[7];
    const float* qkv_b  = (const float*)d_in[8];
    const float* proj_w = (const float*)d_in[9];
    const float* proj_b = (const float*)d_in[10];
    const float* ln2_g  = (const float*)d_in[11];
    const float* ln2_b  = (const float*)d_in[12];
    const float* w1     = (const float*)d_in[13];
    const float* b1     = (const float*)d_in[14];
    const float* w2     = (const float*)d_in[15];
    const float* b2     = (const float*)d_in[16];
    const float* lnf_g  = (const float*)d_in[17];
    const float* lnf_b  = (const float*)d_in[18];
    float* out = (float*)d_out;

    auto al = [](size_t v) { return (v + 255) & ~(size_t)255; };

    // Can we hold all 12 layers' bf16-transposed weights? (≈ 170 MB extra)
    const size_t base_need =
        al((size_t)MPAD * 768 * 4) + al((size_t)MPAD * 768 * 2) +
        al((size_t)MPAD * 2304 * 2) + al((size_t)MPAD * 768 * 2) +
        al((size_t)MPAD * 3072 * 2) + al((size_t)768 * 768 * 2) + 4096;
    const size_t per_layer_w =
        al((size_t)2304 * 768 * 2) + al((size_t)768 * 768 * 2) +
        al((size_t)3072 * 768 * 2) + al((size_t)768 * 3072 * 2);
    const bool batched = ws_size >= base_need + 12 * per_layer_w;
    const int LW = batched ? 12 : 1;

    char* p = (char*)d_ws;
    auto alloc = [&](size_t bytes) {
        char* r = p;
        p += (bytes + 255) & ~(size_t)255;
        return r;
    };
    float* h    = (float*)alloc((size_t)MPAD * 768 * 4);
    u16*  y     = (u16*)alloc((size_t)MPAD * 768 * 2);
    u16*  qkv   = (u16*)alloc((size_t)MPAD * 2304 * 2);
    u16*  attn  = (u16*)alloc((size_t)MPAD * 768 * 2);
    u16*  mid   = (u16*)alloc((size_t)MPAD * 3072 * 2);
    u16*  wq    = (u16*)alloc((size_t)LW * 2304 * 768 * 2);
    u16*  wp    = (u16*)alloc((size_t)LW * 768 * 768 * 2);
    u16*  w1t   = (u16*)alloc((size_t)LW * 3072 * 768 * 2);
    u16*  w2t   = (u16*)alloc((size_t)LW * 768 * 3072 * 2);
    u16*  wcv   = (u16*)alloc((size_t)768 * 768 * 2);
    (void)alloc(4096);
    u16*   patches = mid;          // pre-loop alias
    float* cbuf    = (float*)qkv;  // pre-loop alias (fp32 conv out)

    const dim3 blk(256);

    flatcvt_kernel<<<(768 * 768 / 4 + 255) / 256, blk, 0, stream>>>(conv_w, wcv,
                                                                    768 * 768 / 4);
    im2col_kernel<<<(MPAT * 96 + 255) / 256, blk, 0, stream>>>(x, patches);
    mfma_gemm<64, 0, 0><<<dim3(6, MPAT / 64), blk, 0, stream>>>(
        patches, wcv, conv_b, nullptr, cbuf, MPAT, 768, 768);
    assemble_kernel<<<(MTOT * 192 + 255) / 256, blk, 0, stream>>>(cbuf, cls, pos, h);

    if (batched) {
        // all-layer weight conversion in 4 dispatches (removes 48 in-loop
        // launches; traffic identical)
        wt_kernel<<<dim3(2304 / 32, 768 / 32, 12), blk, 0, stream>>>(
            qkv_w, wq, 768, 2304);
        wt_kernel<<<dim3(768 / 32, 768 / 32, 12), blk, 0, stream>>>(
            proj_w, wp, 768, 768);
        wt_kernel<<<dim3(3072 / 32, 768 / 32, 12), blk, 0, stream>>>(
            w1, w1t, 768, 3072);
        wt_kernel<<<dim3(768 / 32, 3072 / 32, 12), blk, 0, stream>>>(
            w2, w2t, 3072, 768);
    }

    const int my64 = (MTOT + 63) / 64;   // 99 row-blocks for BM=64 gemms

    for (int l = 0; l < L_; l++) {
        u16* wq_l  = wq  + (size_t)(batched ? l : 0) * 2304 * 768;
        u16* wp_l  = wp  + (size_t)(batched ? l : 0) * 768 * 768;
        u16* w1t_l = w1t + (size_t)(batched ? l : 0) * 3072 * 768;
        u16* w2t_l = w2t + (size_t)(batched ? l : 0) * 768 * 3072;
        if (!batched) {
            wt_kernel<<<dim3(2304 / 32, 768 / 32), blk, 0, stream>>>(
                qkv_w + (size_t)l * 768 * 2304, wq_l, 768, 2304);
            wt_kernel<<<dim3(768 / 32, 768 / 32), blk, 0, stream>>>(
                proj_w + (size_t)l * 768 * 768, wp_l, 768, 768);
            wt_kernel<<<dim3(3072 / 32, 768 / 32), blk, 0, stream>>>(
                w1 + (size_t)l * 768 * 3072, w1t_l, 768, 3072);
            wt_kernel<<<dim3(768 / 32, 3072 / 32), blk, 0, stream>>>(
                w2 + (size_t)l * 3072 * 768, w2t_l, 3072, 768);
        }

        ln_kernel<1><<<MTOT, blk, 0, stream>>>(h, ln1_g + l * 768, ln1_b + l * 768,
                                               y, 768);
        mfma_gemm<128, 0, 1><<<dim3(18, 50), blk, 0, stream>>>(
            y, wq_l, qkv_b + l * 2304, nullptr, qkv, MTOT, 2304, 768);
        attn_kernel<<<dim3((NTOK + AQB - 1) / AQB, B_ * H_), blk, 0, stream>>>(
            qkv, attn);
        mfma_gemm<64, 2, 0><<<dim3(6, my64), blk, 0, stream>>>(
            attn, wp_l, proj_b + l * 768, h, h, MTOT, 768, 768);
        ln_kernel<1><<<MTOT, blk, 0, stream>>>(h, ln2_g + l * 768, ln2_b + l * 768,
                                               y, 768);
        mfma_gemm<128, 1, 1><<<dim3(24, 50), blk, 0, stream>>>(
            y, w1t_l, b1 + l * DFF, nullptr, mid, MTOT, DFF, 768);
        mfma_gemm<64, 2, 0><<<dim3(6, my64), blk, 0, stream>>>(
            mid, w2t_l, b2 + l * 768, h, h, MTOT, 768, DFF);
    }

    ln_kernel<0><<<B_, blk, 0, stream>>>(h, lnf_g, lnf_b, out, (size_t)NTOK * 768);
}

// Round 2
// 4330.666 us; speedup vs baseline: 1.1121x; 1.0233x over previous
//
#include <hip/hip_runtime.h>
#include <math.h>

// ---------------- problem constants ----------------
#define B_   8
#define D_   768
#define H_   12
#define L_   12
#define NTOK 785            // 1 + 28*28
#define NPAT 784
#define MTOT (B_ * NTOK)    // 6280
#define MPAT (B_ * NPAT)    // 6272
#define MPAD 6400           // padded row count (multiple of 128)
#define DFF  3072
#define EPS_ 1e-5f

typedef unsigned short u16;
typedef unsigned int   u32;
typedef short s16x8 __attribute__((ext_vector_type(8)));
typedef float f32x4 __attribute__((ext_vector_type(4)));

__device__ __forceinline__ u16 f2b(float f) {
    u32 u = __float_as_uint(f);
    u += 0x7fffu + ((u >> 16) & 1u);   // RNE
    return (u16)(u >> 16);
}
__device__ __forceinline__ float b2f(u16 s) {
    return __uint_as_float(((u32)s) << 16);
}
__device__ __forceinline__ void gload_lds16(const void* g, void* l) {
    __builtin_amdgcn_global_load_lds(
        (const __attribute__((address_space(1))) void*)g,
        (__attribute__((address_space(3))) void*)l, 16, 0, 0);
}
__device__ __forceinline__ float gelu_exact(float x) {
    return 0.5f * x * (1.0f + erff(x * 0.70710678118654752f));
}

// ---------------- bf16 MFMA GEMM ----------------
// C[M,N] = A[M,K](bf16) @ W + bias, with WT[N,K](bf16) = W^T.
// BM x 128 tile (BM in {64,128}), BK=32, 256 threads (4 waves), 2x2 wave grid.
// K-loop is double-buffered with EARLY-ISSUE staging (T3-minimum 2-phase):
//   stage(buf^1, t+1); ds_read+MFMA from buf; __syncthreads (vmcnt drain AFTER
//   compute, not between stage and compute). Load latency hides under MFMA.
// LDS bank conflicts on the b128 fragment reads (64B row stride -> 8-way) are
// fixed by an XOR involution applied on BOTH sides (rule #21): the global
// source k-slot is pre-swizzled with s = (c&3)^(r&3) while the DMA writes LDS
// linearly, and the fragment read uses slot = q^(row&3). Both reduce to
// lane-constant XORs.
// MODE: 0 bias, 1 bias+gelu, 2 bias+residual(R fp32). OUTBF: 1 -> bf16 out.
template <int BM, int MODE, int OUTBF>
__global__ __launch_bounds__(256) void mfma_gemm(
    const u16* __restrict__ A, const u16* __restrict__ WT,
    const float* __restrict__ bias, const float* __restrict__ R,
    void* __restrict__ Cout, int M, int N, int K)
{
    constexpr int MI = BM / 32;          // A row-fragments per wave
    __shared__ u16 As[2][BM * 32];
    __shared__ u16 Bs[2][128 * 32];

    const int bm = blockIdx.y * BM;
    const int bn = blockIdx.x * 128;
    const int t  = threadIdx.x;
    const int wv = t >> 6, ln = t & 63;
    const int wr = wv >> 1, wc = wv & 1;

    f32x4 acc[MI][4];
    const f32x4 z4 = {0.f, 0.f, 0.f, 0.f};
#pragma unroll
    for (int i = 0; i < MI; i++)
#pragma unroll
        for (int j = 0; j < 4; j++) acc[i][j] = z4;

    const int lrow = ln & 15;
    // swizzled 16B-slot index for fragment reads: q ^ (row&3), row&3 == ln&3
    const int sq   = ((ln >> 4) ^ (ln & 3)) * 8;
    // swizzled source slot for staging: (c&3)^(r&3) == (ln&3)^((ln>>2)&3)
    const int ssl  = ((ln & 3) ^ ((ln >> 2) & 3)) * 8;

    auto stage = [&](int kt, int buf) {
#pragma unroll
        for (int g = 0; g < BM / 64; g++) {
            const int c = g * 256 + wv * 64 + ln;       // 16B chunk id
            const int r = c >> 2;
            u16* ldsA = As[buf] + (g * 256 + wv * 64) * 8;   // wave-uniform base
            gload_lds16(A + (size_t)(bm + r) * K + kt + ssl, ldsA);
        }
#pragma unroll
        for (int g = 0; g < 2; g++) {
            const int c = g * 256 + wv * 64 + ln;
            const int r = c >> 2;
            u16* ldsB = Bs[buf] + (g * 256 + wv * 64) * 8;
            gload_lds16(WT + (size_t)(bn + r) * K + kt + ssl, ldsB);
        }
    };

    stage(0, 0);
    __syncthreads();
    int cur = 0;

    for (int kt = 0; kt < K; kt += 32) {
        if (kt + 32 < K) stage(kt + 32, cur ^ 1);

        s16x8 af[MI], bf[4];
#pragma unroll
        for (int i = 0; i < MI; i++)
            af[i] = *(const s16x8*)(As[cur] + (wr * (BM / 2) + i * 16 + lrow) * 32 + sq);
#pragma unroll
        for (int j = 0; j < 4; j++)
            bf[j] = *(const s16x8*)(Bs[cur] + (wc * 64 + j * 16 + lrow) * 32 + sq);
#pragma unroll
        for (int i = 0; i < MI; i++)
#pragma unroll
            for (int j = 0; j < 4; j++)
                acc[i][j] = __builtin_amdgcn_mfma_f32_16x16x32_bf16(
                    af[i], bf[j], acc[i][j], 0, 0, 0);

        __syncthreads();   // vmcnt drain lands AFTER compute; next buf ready
        cur ^= 1;
    }

    const int col_l = ln & 15;
    const int rq    = (ln >> 4) * 4;
#pragma unroll
    for (int j = 0; j < 4; j++) {
        const int col = bn + wc * 64 + j * 16 + col_l;
        const float bj = bias[col];
#pragma unroll
        for (int i = 0; i < MI; i++) {
            const int row0 = bm + wr * (BM / 2) + i * 16 + rq;
#pragma unroll
            for (int rg = 0; rg < 4; rg++) {
                const int row = row0 + rg;
                if (row >= M) continue;
                float v = acc[i][j][rg] + bj;
                if (MODE == 1) v = gelu_exact(v);
                if (MODE == 2) v += R[(size_t)row * N + col];
                if (OUTBF) ((u16*)Cout)[(size_t)row * N + col] = f2b(v);
                else       ((float*)Cout)[(size_t)row * N + col] = v;
            }
        }
    }
}

// ---------------- weight convert + transpose: W[K,N] f32 -> WT[N,K] bf16 ----
// blockIdx.z = layer; per-layer stride is K*N elements for both src and dst.
__global__ __launch_bounds__(256) void wt_kernel(
    const float* __restrict__ W, u16* __restrict__ WT, int K, int N)
{
    const size_t lz = blockIdx.z;
    W  += lz * (size_t)K * N;
    WT += lz * (size_t)K * N;
    __shared__ float tile[32][33];
    const int n0 = blockIdx.x * 32, k0 = blockIdx.y * 32;
    const int r = threadIdx.x >> 3, c4 = (threadIdx.x & 7) * 4;
    const float4 v = *(const float4*)(W + (size_t)(k0 + r) * N + n0 + c4);
    tile[r][c4 + 0] = v.x; tile[r][c4 + 1] = v.y;
    tile[r][c4 + 2] = v.z; tile[r][c4 + 3] = v.w;
    __syncthreads();
    ushort4 o = make_ushort4(f2b(tile[c4 + 0][r]), f2b(tile[c4 + 1][r]),
                             f2b(tile[c4 + 2][r]), f2b(tile[c4 + 3][r]));
    *(ushort4*)(WT + (size_t)(n0 + r) * K + k0 + c4) = o;
}

// ---------------- flat f32 -> bf16 convert ----------------
__global__ __launch_bounds__(256) void flatcvt_kernel(
    const float* __restrict__ in, u16* __restrict__ out, int n4)
{
    const int i = blockIdx.x * 256 + threadIdx.x;
    if (i >= n4) return;
    const float4 v = ((const float4*)in)[i];
    ((ushort4*)out)[i] = make_ushort4(f2b(v.x), f2b(v.y), f2b(v.z), f2b(v.w));
}

// ---------------- LayerNorm (fp32 in, bf16 or fp32 out) ----------------
__device__ __forceinline__ float block_sum(float s, float* red) {
#pragma unroll
    for (int off = 32; off; off >>= 1) s += __shfl_down(s, off, 64);
    const int wid = threadIdx.x >> 6;
    if ((threadIdx.x & 63) == 0) red[wid] = s;
    __syncthreads();
    if (threadIdx.x == 0) red[0] = red[0] + red[1] + red[2] + red[3];
    __syncthreads();
    const float r = red[0];
    __syncthreads();
    return r;
}

template <int OUTBF>
__global__ __launch_bounds__(256) void ln_kernel(
    const float* __restrict__ X, const float* __restrict__ g,
    const float* __restrict__ b, void* __restrict__ Y, size_t row_stride_in)
{
    __shared__ float red[4];
    const int row = blockIdx.x;
    const int t = threadIdx.x;
    const float* x = X + (size_t)row * row_stride_in;

    const float v0 = x[t], v1 = x[t + 256], v2 = x[t + 512];
    const float mean = block_sum(v0 + v1 + v2, red) * (1.0f / 768.0f);
    const float d0 = v0 - mean, d1 = v1 - mean, d2 = v2 - mean;
    const float var = block_sum(d0 * d0 + d1 * d1 + d2 * d2, red) * (1.0f / 768.0f);
    const float rs = rsqrtf(var + EPS_);

    const float o0 = d0 * rs * g[t] + b[t];
    const float o1 = d1 * rs * g[t + 256] + b[t + 256];
    const float o2 = d2 * rs * g[t + 512] + b[t + 512];
    if (OUTBF) {
        u16* y = (u16*)Y + (size_t)row * 768;
        y[t] = f2b(o0); y[t + 256] = f2b(o1); y[t + 512] = f2b(o2);
    } else {
        float* y = (float*)Y + (size_t)row * 768;
        y[t] = o0; y[t + 256] = o1; y[t + 512] = o2;
    }
}

// ---------------- MFMA flash attention ----------------
// Block: one (b,h), 128 q-rows; 4 waves x 32 q-rows (2 row-tiles of 16).
// K-tiles of 64 tokens. QK^T and PV via mfma_f32_16x16x32_bf16 (NT form).
#define AQB  128
#define AKT  64
#define KSTR 72   // u16 row stride: 144B rows -> b128 frag reads at bank floor

__global__ __launch_bounds__(256) void attn_kernel(
    const u16* __restrict__ qkv, u16* __restrict__ out)
{
    __shared__ u16 Ks[AKT * KSTR];
    __shared__ u16 Vt[64 * KSTR];
    __shared__ u16 Ps[4 * 32 * KSTR];

    const int bh = blockIdx.y;
    const int b  = bh / H_, hh = bh % H_;
    const int q0 = blockIdx.x * AQB;
    const int t  = threadIdx.x;
    const int w  = t >> 6, ln = t & 63;
    const int lrow = ln & 15, quad = ln >> 4;
    const size_t tokbase = (size_t)b * NTOK;

    s16x8 aq[2][2];
#pragma unroll
    for (int rowt = 0; rowt < 2; rowt++) {
        int qr = q0 + w * 32 + rowt * 16 + lrow;
        if (qr > NTOK - 1) qr = NTOK - 1;
        const u16* qp = qkv + (tokbase + qr) * 2304 + hh * 64 + quad * 8;
        aq[rowt][0] = *(const s16x8*)(qp);
        aq[rowt][1] = *(const s16x8*)(qp + 32);
    }

    f32x4 acc_o[2][4];
    const f32x4 z4 = {0.f, 0.f, 0.f, 0.f};
#pragma unroll
    for (int i = 0; i < 2; i++)
#pragma unroll
        for (int j = 0; j < 4; j++) acc_o[i][j] = z4;
    float m_r[2][4], l_r[2][4];
#pragma unroll
    for (int i = 0; i < 2; i++)
#pragma unroll
        for (int j = 0; j < 4; j++) { m_r[i][j] = -1e30f; l_r[i][j] = 0.f; }

    for (int j0 = 0; j0 < NTOK; j0 += AKT) {
        __syncthreads();
#pragma unroll
        for (int g = 0; g < 2; g++) {
            const int c = g * 256 + t;
            const int j = c >> 3, dc = c & 7;
            int jj = j0 + j; if (jj > NTOK - 1) jj = NTOK - 1;
            const s16x8 kv = *(const s16x8*)(
                qkv + (tokbase + jj) * 2304 + 768 + hh * 64 + dc * 8);
            *(s16x8*)(Ks + j * KSTR + dc * 8) = kv;
        }
#pragma unroll
        for (int g = 0; g < 2; g++) {
            const int c = g * 256 + t;
            const int j = c & 63, dc = c >> 6;
            int jj = j0 + j; if (jj > NTOK - 1) jj = NTOK - 1;
            const s16x8 vv = *(const s16x8*)(
                qkv + (tokbase + jj) * 2304 + 1536 + hh * 64 + dc * 8);
#pragma unroll
            for (int e = 0; e < 8; e++)
                Vt[(dc * 8 + e) * KSTR + j] = (u16)((const short*)&vv)[e];
        }
        __syncthreads();

        f32x4 acc_s[2][4];
#pragma unroll
        for (int i = 0; i < 2; i++)
#pragma unroll
            for (int j = 0; j < 4; j++) acc_s[i][j] = z4;
#pragma unroll
        for (int jt = 0; jt < 4; jt++) {
            const s16x8 bk0 =
                *(const s16x8*)(Ks + (jt * 16 + lrow) * KSTR + quad * 8);
            const s16x8 bk1 =
                *(const s16x8*)(Ks + (jt * 16 + lrow) * KSTR + 32 + quad * 8);
#pragma unroll
            for (int rowt = 0; rowt < 2; rowt++) {
                acc_s[rowt][jt] = __builtin_amdgcn_mfma_f32_16x16x32_bf16(
                    aq[rowt][0], bk0, acc_s[rowt][jt], 0, 0, 0);
                acc_s[rowt][jt] = __builtin_amdgcn_mfma_f32_16x16x32_bf16(
                    aq[rowt][1], bk1, acc_s[rowt][jt], 0, 0, 0);
            }
        }
        const f32x4 ninf = {-1e30f, -1e30f, -1e30f, -1e30f};
#pragma unroll
        for (int jt = 0; jt < 4; jt++) {
            const bool valid = (j0 + jt * 16 + lrow) < NTOK;
#pragma unroll
            for (int rowt = 0; rowt < 2; rowt++)
                acc_s[rowt][jt] = valid ? acc_s[rowt][jt] * 0.125f : ninf;
        }

#pragma unroll
        for (int rowt = 0; rowt < 2; rowt++) {
#pragma unroll
            for (int rg = 0; rg < 4; rg++) {
                float mx = fmaxf(fmaxf(acc_s[rowt][0][rg], acc_s[rowt][1][rg]),
                                 fmaxf(acc_s[rowt][2][rg], acc_s[rowt][3][rg]));
                mx = fmaxf(mx, __shfl_xor(mx, 1, 64));
                mx = fmaxf(mx, __shfl_xor(mx, 2, 64));
                mx = fmaxf(mx, __shfl_xor(mx, 4, 64));
                mx = fmaxf(mx, __shfl_xor(mx, 8, 64));
                const float nm = fmaxf(m_r[rowt][rg], mx);
                const float al = __expf(m_r[rowt][rg] - nm);
                m_r[rowt][rg] = nm;
                u16* prow = Ps + (size_t)(w * 32 + rowt * 16 + quad * 4 + rg) * KSTR
                            + lrow;
                float ps = 0.f;
#pragma unroll
                for (int jt = 0; jt < 4; jt++) {
                    const float p = __expf(acc_s[rowt][jt][rg] - nm);
                    ps += p;
                    prow[jt * 16] = f2b(p);
                }
                ps += __shfl_xor(ps, 1, 64);
                ps += __shfl_xor(ps, 2, 64);
                ps += __shfl_xor(ps, 4, 64);
                ps += __shfl_xor(ps, 8, 64);
                l_r[rowt][rg] = l_r[rowt][rg] * al + ps;
#pragma unroll
                for (int dt = 0; dt < 4; dt++) acc_o[rowt][dt][rg] *= al;
            }
        }

#pragma unroll
        for (int jc = 0; jc < 2; jc++) {
            const s16x8 ap0 = *(const s16x8*)(
                Ps + (w * 32 + lrow) * KSTR + jc * 32 + quad * 8);
            const s16x8 ap1 = *(const s16x8*)(
                Ps + (w * 32 + 16 + lrow) * KSTR + jc * 32 + quad * 8);
#pragma unroll
            for (int dt = 0; dt < 4; dt++) {
                const s16x8 bv = *(const s16x8*)(
                    Vt + (dt * 16 + lrow) * KSTR + jc * 32 + quad * 8);
                acc_o[0][dt] = __builtin_amdgcn_mfma_f32_16x16x32_bf16(
                    ap0, bv, acc_o[0][dt], 0, 0, 0);
                acc_o[1][dt] = __builtin_amdgcn_mfma_f32_16x16x32_bf16(
                    ap1, bv, acc_o[1][dt], 0, 0, 0);
            }
        }
    }

#pragma unroll
    for (int rowt = 0; rowt < 2; rowt++) {
#pragma unroll
        for (int rg = 0; rg < 4; rg++) {
            const int tok = q0 + w * 32 + rowt * 16 + quad * 4 + rg;
            if (tok >= NTOK) continue;
            const float inv = 1.0f / l_r[rowt][rg];
            u16* dst = out + (tokbase + tok) * D_ + hh * 64 + lrow;
#pragma unroll
            for (int dt = 0; dt < 4; dt++)
                dst[dt * 16] = f2b(acc_o[rowt][dt][rg] * inv);
        }
    }
}

// ---------------- im2col (fp32 -> bf16 patches) ----------------
__global__ __launch_bounds__(256) void im2col_kernel(
    const float* __restrict__ x, u16* __restrict__ patches)
{
    const int idx = blockIdx.x * 256 + threadIdx.x;  // over MPAT*96 8-chunks
    if (idx >= MPAT * 96) return;
    const int prow = idx / 96;
    const int c8 = (idx % 96) * 8;
    const int bb = prow / NPAT;
    const int pp = prow % NPAT;
    const int gy = pp / 28, gx = pp % 28;
    const int c = c8 >> 8;
    const int rem = c8 & 255;
    const int py = rem >> 4, px = rem & 15;
    const float* src =
        x + (((size_t)(bb * 3 + c) * 448 + gy * 16 + py) * 448 + gx * 16 + px);
    const float4 a = *(const float4*)src;
    const float4 bq = *(const float4*)(src + 4);
    u16* dst = patches + (size_t)prow * 768 + c8;
    uint4 w4;
    w4.x = (u32)f2b(a.x) | ((u32)f2b(a.y) << 16);
    w4.y = (u32)f2b(a.z) | ((u32)f2b(a.w) << 16);
    w4.z = (u32)f2b(bq.x) | ((u32)f2b(bq.y) << 16);
    w4.w = (u32)f2b(bq.z) | ((u32)f2b(bq.w) << 16);
    *(uint4*)dst = w4;
}

// ---------------- assemble h = [cls|conv_out] + pos (fp32) ----------------
__global__ __launch_bounds__(256) void assemble_kernel(
    const float* __restrict__ conv_out, const float* __restrict__ cls,
    const float* __restrict__ pos, float* __restrict__ h)
{
    const int idx = blockIdx.x * 256 + threadIdx.x;  // over MTOT*192 float4s
    if (idx >= MTOT * 192) return;
    const int row = idx / 192;
    const int d = (idx % 192) * 4;
    const int bb = row / NTOK, n = row % NTOK;
    const float4 pv = *(const float4*)(pos + (size_t)n * 768 + d);
    float4 v;
    if (n == 0) {
        const float4 cv = *(const float4*)(cls + d);
        v = make_float4(cv.x + pv.x, cv.y + pv.y, cv.z + pv.z, cv.w + pv.w);
    } else {
        const float4 co =
            *(const float4*)(conv_out + (size_t)(bb * NPAT + n - 1) * 768 + d);
        v = make_float4(co.x + pv.x, co.y + pv.y, co.z + pv.z, co.w + pv.w);
    }
    *(float4*)(h + (size_t)row * 768 + d) = v;
}

// ---------------- host orchestration ----------------
extern "C" void kernel_launch(void* const* d_in, const int* in_sizes, int n_in,
                              void* d_out, int out_size, void* d_ws, size_t ws_size,
                              hipStream_t stream)
{
    const float* x      = (const float*)d_in[0];
    const float* conv_w = (const float*)d_in[1];
    const float* conv_b = (const float*)d_in[2];
    const float* cls    = (const float*)d_in[3];
    const float* pos    = (const float*)d_in[4];
    const float* ln1_g  = (const float*)d_in[5];
    const float* ln1_b  = (const float*)d_in[6];
    const float* qkv_w  = (const float*)d_in[7];
    const float* qkv_b  = (const float*)d_in[8];
    const float* proj_w = (const float*)d_in[9];
    const float* proj_b = (const float*)d_in[10];
    const float* ln2_g  = (const float*)d_in[11];
    const float* ln2_b  = (const float*)d_in[12];
    const float* w1     = (const float*)d_in[13];
    const float* b1     = (const float*)d_in[14];
    const float* w2     = (const float*)d_in[15];
    const float* b2     = (const float*)d_in[16];
    const float* lnf_g  = (const float*)d_in[17];
    const float* lnf_b  = (const float*)d_in[18];
    float* out = (float*)d_out;

    auto al = [](size_t v) { return (v + 255) & ~(size_t)255; };

    const size_t base_need =
        al((size_t)MPAD * 768 * 4) + al((size_t)MPAD * 768 * 2) +
        al((size_t)MPAD * 2304 * 2) + al((size_t)MPAD * 768 * 2) +
        al((size_t)MPAD * 3072 * 2) + al((size_t)768 * 768 * 2) + 4096;
    const size_t per_layer_w =
        al((size_t)2304 * 768 * 2) + al((size_t)768 * 768 * 2) +
        al((size_t)3072 * 768 * 2) + al((size_t)768 * 3072 * 2);
    const bool batched = ws_size >= base_need + 12 * per_layer_w;
    const int LW = batched ? 12 : 1;

    char* p = (char*)d_ws;
    auto alloc = [&](size_t bytes) {
        char* r = p;
        p += (bytes + 255) & ~(size_t)255;
        return r;
    };
    float* h    = (float*)alloc((size_t)MPAD * 768 * 4);
    u16*  y     = (u16*)alloc((size_t)MPAD * 768 * 2);
    u16*  qkv   = (u16*)alloc((size_t)MPAD * 2304 * 2);
    u16*  attn  = (u16*)alloc((size_t)MPAD * 768 * 2);
    u16*  mid   = (u16*)alloc((size_t)MPAD * 3072 * 2);
    u16*  wq    = (u16*)alloc((size_t)LW * 2304 * 768 * 2);
    u16*  wp    = (u16*)alloc((size_t)LW * 768 * 768 * 2);
    u16*  w1t   = (u16*)alloc((size_t)LW * 3072 * 768 * 2);
    u16*  w2t   = (u16*)alloc((size_t)LW * 768 * 3072 * 2);
    u16*  wcv   = (u16*)alloc((size_t)768 * 768 * 2);
    (void)alloc(4096);
    u16*   patches = mid;          // pre-loop alias
    float* cbuf    = (float*)qkv;  // pre-loop alias (fp32 conv out)

    const dim3 blk(256);

    flatcvt_kernel<<<(768 * 768 / 4 + 255) / 256, blk, 0, stream>>>(conv_w, wcv,
                                                                    768 * 768 / 4);
    im2col_kernel<<<(MPAT * 96 + 255) / 256, blk, 0, stream>>>(x, patches);
    mfma_gemm<64, 0, 0><<<dim3(6, MPAT / 64), blk, 0, stream>>>(
        patches, wcv, conv_b, nullptr, cbuf, MPAT, 768, 768);
    assemble_kernel<<<(MTOT * 192 + 255) / 256, blk, 0, stream>>>(cbuf, cls, pos, h);

    if (batched) {
        wt_kernel<<<dim3(2304 / 32, 768 / 32, 12), blk, 0, stream>>>(
            qkv_w, wq, 768, 2304);
        wt_kernel<<<dim3(768 / 32, 768 / 32, 12), blk, 0, stream>>>(
            proj_w, wp, 768, 768);
        wt_kernel<<<dim3(3072 / 32, 768 / 32, 12), blk, 0, stream>>>(
            w1, w1t, 768, 3072);
        wt_kernel<<<dim3(768 / 32, 3072 / 32, 12), blk, 0, stream>>>(
            w2, w2t, 3072, 768);
    }

    const int my64 = (MTOT + 63) / 64;   // 99 row-blocks for BM=64 gemms

    for (int l = 0; l < L_; l++) {
        u16* wq_l  = wq  + (size_t)(batched ? l : 0) * 2304 * 768;
        u16* wp_l  = wp  + (size_t)(batched ? l : 0) * 768 * 768;
        u16* w1t_l = w1t + (size_t)(batched ? l : 0) * 3072 * 768;
        u16* w2t_l = w2t + (size_t)(batched ? l : 0) * 768 * 3072;
        if (!batched) {
            wt_kernel<<<dim3(2304 / 32, 768 / 32), blk, 0, stream>>>(
                qkv_w + (size_t)l * 768 * 2304, wq_l, 768, 2304);
            wt_kernel<<<dim3(768 / 32, 768 / 32), blk, 0, stream>>>(
                proj_w + (size_t)l * 768 * 768, wp_l, 768, 768);
            wt_kernel<<<dim3(3072 / 32, 768 / 32), blk, 0, stream>>>(
                w1 + (size_t)l * 768 * 3072, w1t_l, 768, 3072);
            wt_kernel<<<dim3(768 / 32, 3072 / 32), blk, 0, stream>>>(
                w2 + (size_t)l * 3072 * 768, w2t_l, 3072, 768);
        }

        ln_kernel<1><<<MTOT, blk, 0, stream>>>(h, ln1_g + l * 768, ln1_b + l * 768,
                                               y, 768);
        mfma_gemm<128, 0, 1><<<dim3(18, 50), blk, 0, stream>>>(
            y, wq_l, qkv_b + l * 2304, nullptr, qkv, MTOT, 2304, 768);
        attn_kernel<<<dim3((NTOK + AQB - 1) / AQB, B_ * H_), blk, 0, stream>>>(
            qkv, attn);
        mfma_gemm<64, 2, 0><<<dim3(6, my64), blk, 0, stream>>>(
            attn, wp_l, proj_b + l * 768, h, h, MTOT, 768, 768);
        ln_kernel<1><<<MTOT, blk, 0, stream>>>(h, ln2_g + l * 768, ln2_b + l * 768,
                                               y, 768);
        mfma_gemm<128, 1, 1><<<dim3(24, 50), blk, 0, stream>>>(
            y, w1t_l, b1 + l * DFF, nullptr, mid, MTOT, DFF, 768);
        mfma_gemm<64, 2, 0><<<dim3(6, my64), blk, 0, stream>>>(
            mid, w2t_l, b2 + l * 768, h, h, MTOT, 768, DFF);
    }

    ln_kernel<0><<<B_, blk, 0, stream>>>(h, lnf_g, lnf_b, out, (size_t)NTOK * 768);
}